// Round 8
// baseline (73.806 us; speedup 1.0000x reference)
//
#include <hip/hip_runtime.h>

typedef float v2f __attribute__((ext_vector_type(2)));

#define B_ 64
#define T_ 2048
#define D_ 512
#define K_ 8
#define NCHUNK 8
#define ROWS_PER_CHUNK (T_ / NCHUNK)            // 256
#define WAVES 4
#define THREADS (WAVES * 64)                    // 256
#define ROWS_PER_WAVE (ROWS_PER_CHUNK / WAVES)  // 64
#define PAIRS (ROWS_PER_WAVE / 2)               // 32
#define LOG2E 1.44269504088896340736f

// device exp2: direct v_exp_f32 builtin (plain __exp2f collides with a glibc
// math.h prototype -- round-5 compile failure)
__device__ __forceinline__ float dev_exp2(float v) {
  return __builtin_amdgcn_exp2f(v);
}

// Wave64 all-reduce, 100% VALU pipe, all via builtins (compiler-managed
// hazards; raw asm DPP corrupted results in round 4, and permlane*_swap with
// identical operands self-coalesced into a broken self-swap in round 7).
// Canonical GCN pattern: 4x row_ror -> each 16-lane row holds its row-sum;
// row_bcast15 (mask 0xA) adds row0->row1, row2->row3; row_bcast31 (mask 0xC)
// adds (row0+row1) into rows 2,3; lane 63 then holds the full sum;
// readlane(63) broadcasts it as an SGPR.
template <int CTRL, int RMASK>
__device__ __forceinline__ float dpp_add(float v) {
  int vi = __builtin_bit_cast(int, v);
  int sh = __builtin_amdgcn_update_dpp(0, vi, CTRL, RMASK, 0xF, true);
  return v + __builtin_bit_cast(float, sh);
}

__device__ __forceinline__ float wave_sum(float v) {
  v = dpp_add<0x121, 0xF>(v);  // row_ror:1
  v = dpp_add<0x122, 0xF>(v);  // row_ror:2
  v = dpp_add<0x124, 0xF>(v);  // row_ror:4
  v = dpp_add<0x128, 0xF>(v);  // row_ror:8  -> row sums
  v = dpp_add<0x142, 0xA>(v);  // row_bcast15 into rows 1,3
  v = dpp_add<0x143, 0xC>(v);  // row_bcast31 into rows 2,3 -> lane63 = total
  return __builtin_bit_cast(float,
      __builtin_amdgcn_readlane(__builtin_bit_cast(int, v), 63));
}

// Kernel 1: fused logits -> softmax -> weighted accumulation, single pass
// over x. 2 waves/SIMD (VGPR-capped); ping-pong row-pair buffers. Lane owns
// d in {lane*4..+4} u {256+lane*4..+4} -> every dwordx4 wave-load is a
// contiguous 1KB segment. Dot + acc arithmetic in float2 ext-vectors so the
// backend can emit v_pk_fma_f32 (full-rate fp32; scalar v_fma is half-rate).
// w/bias pre-scaled by log2e so softmax is pure exp2 (acc uses raw xv).
__global__ __launch_bounds__(THREADS, 2) void k1_accum(
    const float* __restrict__ x, const float* __restrict__ attn_w,
    const float* __restrict__ attn_b, float* __restrict__ ax_part,
    float* __restrict__ asum_part) {
  const int blk = blockIdx.x;
  const int b = blk / NCHUNK;
  const int chunk = blk % NCHUNK;
  const int tid = threadIdx.x;
  const int wave = tid >> 6;
  const int lane = tid & 63;
  const int lane4 = lane << 2;

  v2f w2[K_][4];
#pragma unroll
  for (int k = 0; k < K_; ++k) {
    const float4 w0 = *reinterpret_cast<const float4*>(attn_w + k * D_ + lane4);
    const float4 w1 = *reinterpret_cast<const float4*>(attn_w + k * D_ + 256 + lane4);
    w2[k][0] = (v2f){w0.x * LOG2E, w0.y * LOG2E};
    w2[k][1] = (v2f){w0.z * LOG2E, w0.w * LOG2E};
    w2[k][2] = (v2f){w1.x * LOG2E, w1.y * LOG2E};
    w2[k][3] = (v2f){w1.z * LOG2E, w1.w * LOG2E};
  }
  float bias[K_];
#pragma unroll
  for (int k = 0; k < K_; ++k) bias[k] = attn_b[k] * LOG2E;

  v2f acc2[K_][4];
  float asum[K_];
#pragma unroll
  for (int k = 0; k < K_; ++k) {
    asum[k] = 0.f;
#pragma unroll
    for (int j = 0; j < 4; ++j) acc2[k][j] = (v2f){0.f, 0.f};
  }

  const float* xw = x + ((size_t)b * T_ + (size_t)chunk * ROWS_PER_CHUNK +
                         (size_t)wave * ROWS_PER_WAVE) * (size_t)D_;

#define LOADPAIR(P00, P01, P10, P11, pairidx)                                  \
  do {                                                                         \
    const float* rp_ = xw + (size_t)(2 * (pairidx)) * D_;                      \
    P00 = *reinterpret_cast<const float4*>(rp_ + lane4);                       \
    P01 = *reinterpret_cast<const float4*>(rp_ + 256 + lane4);                 \
    P10 = *reinterpret_cast<const float4*>(rp_ + D_ + lane4);                  \
    P11 = *reinterpret_cast<const float4*>(rp_ + D_ + 256 + lane4);            \
  } while (0)

  auto process = [&](const float4& r0lo, const float4& r0hi,
                     const float4& r1lo, const float4& r1hi) {
    const v2f x0[4] = {{r0lo.x, r0lo.y}, {r0lo.z, r0lo.w},
                       {r0hi.x, r0hi.y}, {r0hi.z, r0hi.w}};
    const v2f x1[4] = {{r1lo.x, r1lo.y}, {r1lo.z, r1lo.w},
                       {r1hi.x, r1hi.y}, {r1hi.z, r1hi.w}};
    float p0[K_], p1[K_];
#pragma unroll
    for (int k = 0; k < K_; ++k) {
      v2f s0 = x0[0] * w2[k][0];
      v2f s1 = x1[0] * w2[k][0];
#pragma unroll
      for (int j = 1; j < 4; ++j) {
        s0 += x0[j] * w2[k][j];
        s1 += x1[j] * w2[k][j];
      }
      p0[k] = s0.x + s0.y;
      p1[k] = s1.x + s1.y;
    }
#pragma unroll
    for (int k = 0; k < K_; ++k) {
      p0[k] = wave_sum(p0[k]);
      p1[k] = wave_sum(p1[k]);
    }
    // softmax over K=8 in exp2 domain; no max-subtraction (logits ~ N(0,1),
    // exp2 safe in fp32; ratio identical to the max-subtracted form).
    float t0 = 0.f, t1 = 0.f;
    float e0[K_], e1[K_];
#pragma unroll
    for (int k = 0; k < K_; ++k) {
      e0[k] = dev_exp2(p0[k] + bias[k]);
      e1[k] = dev_exp2(p1[k] + bias[k]);
      t0 += e0[k];
      t1 += e1[k];
    }
    const float inv0 = __builtin_amdgcn_rcpf(t0);
    const float inv1 = __builtin_amdgcn_rcpf(t1);
#pragma unroll
    for (int k = 0; k < K_; ++k) {
      const float a0 = e0[k] * inv0;
      const float a1 = e1[k] * inv1;
      asum[k] += a0 + a1;
      const v2f av0 = {a0, a0}, av1 = {a1, a1};
#pragma unroll
      for (int j = 0; j < 4; ++j)
        acc2[k][j] += av0 * x0[j] + av1 * x1[j];
    }
  };

  float4 A00, A01, A10, A11, B00, B01, B10, B11;
  LOADPAIR(A00, A01, A10, A11, 0);
  LOADPAIR(B00, B01, B10, B11, 1);

  for (int p = 0; p < PAIRS; p += 2) {
    process(A00, A01, A10, A11);
    const int pa = (p + 2 < PAIRS) ? (p + 2) : p;  // clamped refill (in-bounds)
    LOADPAIR(A00, A01, A10, A11, pa);
    process(B00, B01, B10, B11);
    const int pb = (p + 3 < PAIRS) ? (p + 3) : (p + 1);
    LOADPAIR(B00, B01, B10, B11, pb);
  }
#undef LOADPAIR

  // cross-wave reduction in LDS (sequential rounds -> deterministic)
  __shared__ __align__(16) float lds_ax[K_ * D_];  // 16 KiB
  __shared__ float lds_asum[WAVES][K_];
  if (lane == 0) {
#pragma unroll
    for (int k = 0; k < K_; ++k) lds_asum[wave][k] = asum[k];
  }
  for (int wv = 0; wv < WAVES; ++wv) {
    if (wave == wv) {
#pragma unroll
      for (int k = 0; k < K_; ++k)
#pragma unroll
        for (int j = 0; j < 8; ++j) {
          const float val = (j & 1) ? acc2[k][j >> 1].y : acc2[k][j >> 1].x;
          const int d = (j < 4) ? (lane4 + j) : (256 + lane4 + j - 4);
          if (wv == 0)
            lds_ax[k * D_ + d] = val;
          else
            lds_ax[k * D_ + d] += val;
        }
    }
    __syncthreads();
  }

  float4* outp = reinterpret_cast<float4*>(ax_part + (size_t)blk * (K_ * D_));
  const float4* lp = reinterpret_cast<const float4*>(lds_ax);
#pragma unroll
  for (int i = 0; i < (K_ * D_ / 4) / THREADS; ++i)  // 4 iters
    outp[tid + i * THREADS] = lp[tid + i * THREADS];
  if (tid < K_) {
    float s = 0.f;
#pragma unroll
    for (int wv = 0; wv < WAVES; ++wv) s += lds_asum[wv][tid];
    asum_part[blk * K_ + tid] = s;
  }
}

// Kernel 2: reduce chunk partials, subtract asum*centers, L2-normalize per b.
#define K2_THREADS 1024
__global__ __launch_bounds__(K2_THREADS) void k2_finalize(
    const float* __restrict__ ax_part, const float* __restrict__ asum_part,
    const float* __restrict__ centers, float* __restrict__ out) {
  const int b = blockIdx.x;
  const int tid = threadIdx.x;
  const int wave = tid >> 6;
  const int lane = tid & 63;

  __shared__ float s_asum[K_];
  if (tid < K_) {
    float s = 0.f;
#pragma unroll
    for (int c = 0; c < NCHUNK; ++c) s += asum_part[(b * NCHUNK + c) * K_ + tid];
    s_asum[tid] = s;
  }
  __syncthreads();

  const int NPT = (K_ * D_) / K2_THREADS;  // 4
  float pooled[NPT];
  float sq = 0.f;
  const float* base = ax_part + (size_t)b * NCHUNK * (K_ * D_);
#pragma unroll
  for (int i = 0; i < NPT; ++i) {
    const int idx = tid + i * K2_THREADS;
    float v = 0.f;
#pragma unroll
    for (int c = 0; c < NCHUNK; ++c) v += base[(size_t)c * (K_ * D_) + idx];
    const int k = idx >> 9;  // idx / D_
    v -= s_asum[k] * centers[idx];
    pooled[i] = v;
    sq = fmaf(v, v, sq);
  }

#pragma unroll
  for (int m = 32; m; m >>= 1) sq += __shfl_xor(sq, m);
  __shared__ float s_sq[K2_THREADS / 64];
  if (lane == 0) s_sq[wave] = sq;
  __syncthreads();
  float tot = 0.f;
#pragma unroll
  for (int wv = 0; wv < K2_THREADS / 64; ++wv) tot += s_sq[wv];
  const float invn = 1.0f / fmaxf(__builtin_sqrtf(tot), 1e-12f);

#pragma unroll
  for (int i = 0; i < NPT; ++i)
    out[(size_t)b * (K_ * D_) + tid + i * K2_THREADS] = pooled[i] * invn;
}

extern "C" void kernel_launch(void* const* d_in, const int* in_sizes, int n_in,
                              void* d_out, int out_size, void* d_ws, size_t ws_size,
                              hipStream_t stream) {
  (void)in_sizes; (void)n_in; (void)out_size; (void)ws_size;
  const float* x = (const float*)d_in[0];
  const float* centers = (const float*)d_in[1];
  const float* attn_w = (const float*)d_in[2];
  const float* attn_b = (const float*)d_in[3];
  float* out = (float*)d_out;

  float* ax_part = (float*)d_ws;                               // B*NCHUNK*K*D floats (8 MiB)
  float* asum_part = ax_part + (size_t)B_ * NCHUNK * K_ * D_;  // B*NCHUNK*K floats

  k1_accum<<<B_ * NCHUNK, THREADS, 0, stream>>>(x, attn_w, attn_b, ax_part, asum_part);
  k2_finalize<<<B_, K2_THREADS, 0, stream>>>(ax_part, asum_part, centers, out);
}